// Round 13
// baseline (34.923 us; speedup 1.0000x reference)
//
#include <hip/hip_runtime.h>
#include <stdint.h>

#define NPROP 2048
#define NCLS  2
#define KDET  100
#define BT    512
#define NMS_TH 0.4f

// decode the monotone-encoded score from the high word of a sort key
__device__ __forceinline__ float dec_score(uint64_t k) {
    uint32_t u = ~(uint32_t)(k >> 32);
    uint32_t bits = (u & 0x80000000u) ? (u & 0x7FFFFFFFu) : ~u;
    return __uint_as_float(bits);
}

// wave-uniform lane broadcast via v_readlane (no DS op; bit-exact)
__device__ __forceinline__ float bcastf(float v, int srclane) {
    return __uint_as_float((uint32_t)__builtin_amdgcn_readlane(__float_as_int(v), srclane));
}

// reference-rounding IoU on offset coords (a vs b), both precomputed with areas
__device__ __forceinline__ float iou5(float ax1, float ay1, float ax2, float ay2, float aa,
                                      float bx1, float by1, float bx2, float by2, float ba) {
    float ltx = fmaxf(ax1, bx1), lty = fmaxf(ay1, by1);
    float rbx = fminf(ax2, bx2), rby = fminf(ay2, by2);
    float iw = fmaxf(__fsub_rn(rbx, ltx), 0.0f);
    float ih = fmaxf(__fsub_rn(rby, lty), 0.0f);
    float inter = __fmul_rn(iw, ih);
    float denom = __fadd_rn(__fsub_rn(__fadd_rn(aa, ba), inter), 1e-9f);
    return __fdiv_rn(inter, denom);
}

// decode+clip+score one proposal: bit-identical to the validated R5 path
__device__ __forceinline__ void decode_one(
    const float* __restrict__ clss, const float* __restrict__ regs,
    const float* __restrict__ qlts, const float* __restrict__ props,
    int b, int i, float4& boxOut, uint64_t& keyOut, float& mxOut)
{
    const float CLIPV = 4.135166556742356f;   // log(1000/16)
    float4 p  = ((const float4*)props)[b * NPROP + i];
    float4 rg = ((const float4*)regs)[b * NPROP + i];
    float2 cc = ((const float2*)clss)[b * NPROP + i];
    float  qv = qlts[(size_t)b * NPROP + i];

    float w  = __fsub_rn(p.z, p.x);
    float h  = __fsub_rn(p.w, p.y);
    float cx = __fadd_rn(p.x, __fmul_rn(0.5f, w));
    float cy = __fadd_rn(p.y, __fmul_rn(0.5f, h));
    float dx = __fdiv_rn(rg.x, 10.0f);
    float dy = __fdiv_rn(rg.y, 10.0f);
    float dw = fminf(__fdiv_rn(rg.z, 5.0f), CLIPV);
    float dh = fminf(__fdiv_rn(rg.w, 5.0f), CLIPV);
    float pcx = __fadd_rn(__fmul_rn(dx, w), cx);
    float pcy = __fadd_rn(__fmul_rn(dy, h), cy);
    float pw  = __fmul_rn(expf(dw), w);
    float ph  = __fmul_rn(expf(dh), h);
    float x1 = __fsub_rn(pcx, __fmul_rn(0.5f, pw));
    float y1 = __fsub_rn(pcy, __fmul_rn(0.5f, ph));
    float x2 = __fadd_rn(pcx, __fmul_rn(0.5f, pw));
    float y2 = __fadd_rn(pcy, __fmul_rn(0.5f, ph));
    x1 = fminf(fmaxf(x1, 0.0f), 512.0f);
    y1 = fminf(fmaxf(y1, 0.0f), 512.0f);
    x2 = fminf(fmaxf(x2, 0.0f), 512.0f);
    y2 = fminf(fmaxf(y2, 0.0f), 512.0f);
    bool small_ok = (__fsub_rn(x2, x1) >= 0.01f) && (__fsub_rn(y2, y1) >= 0.01f);

    float m  = fmaxf(cc.x, cc.y);
    float e0 = expf(__fsub_rn(cc.x, m));
    float e1 = expf(__fsub_rn(cc.y, m));
    float raw = __fdiv_rn(e1, __fadd_rn(e0, e1));
    float sq  = __fdiv_rn(1.0f, __fadd_rn(1.0f, expf(-qv)));
    float score = __fmul_rn(sq, raw);
    bool valid = (raw > 0.05f) && small_ok;
    float masked = valid ? score : -1.0f;

    boxOut = make_float4(x1, y1, x2, y2);
    uint32_t fb = __float_as_uint(masked);
    uint32_t u  = (fb & 0x80000000u) ? ~fb : (fb | 0x80000000u); // monotone encode
    keyOut = ((uint64_t)(~u) << 32) | (uint32_t)i;               // asc = score desc, idx asc
    mxOut = fmaxf(fmaxf(x1, y1), fmaxf(x2, y2));
}

// register-resident bitonic sort of 2048 u64 keys (4 consecutive/thread) — fallback path
__device__ __forceinline__ void bitonic2048(uint64_t key[4], uint64_t* skey,
                                            int idxBase, int lane)
{
    for (int k = 2; k <= NPROP; k <<= 1) {
        for (int j = k >> 1; j > 0; j >>= 1) {
            if (j >= 256) {
                __syncthreads();
#pragma unroll
                for (int r = 0; r < 4; ++r) {
                    int idx = idxBase + r;
                    skey[(idx >> 2) | ((idx & 3) << 9)] = key[r];
                }
                __syncthreads();
#pragma unroll
                for (int r = 0; r < 4; ++r) {
                    int idx  = idxBase + r;
                    int pidx = idx ^ j;
                    uint64_t o = skey[(pidx >> 2) | ((pidx & 3) << 9)];
                    bool takeMin = (((idx & k) == 0) == ((idx & j) == 0));
                    bool lt = key[r] < o;
                    uint64_t mn = lt ? key[r] : o, mx = lt ? o : key[r];
                    key[r] = takeMin ? mn : mx;
                }
            } else if (j >= 4) {
                int lx = j >> 2;
#pragma unroll
                for (int r = 0; r < 4; ++r) {
                    int idx = idxBase + r;
                    uint64_t o = __shfl_xor(key[r], lx, 64);
                    bool takeMin = (((idx & k) == 0) == ((lane & lx) == 0));
                    bool lt = key[r] < o;
                    uint64_t mn = lt ? key[r] : o, mx = lt ? o : key[r];
                    key[r] = takeMin ? mn : mx;
                }
            } else {
#pragma unroll
                for (int r = 0; r < 4; ++r) {
                    if ((r & j) == 0) {
                        int rh = r | j;
                        int idx = idxBase + r;
                        bool up = ((idx & k) == 0);
                        uint64_t a = key[r], c2 = key[rh];
                        bool lt = a < c2;
                        uint64_t mn = lt ? a : c2, mx = lt ? c2 : a;
                        key[r] = up ? mn : mx; key[rh] = up ? mx : mn;
                    }
                }
            }
        }
    }
}

// in-wave bitonic sort of ELEMS u64 keys, EPL keys/lane (wave 0 only; zero barriers)
template<int ELEMS, int EPL>
__device__ __forceinline__ void wavesortN(uint64_t* buf, int lane)
{
    uint64_t q[EPL];
#pragma unroll
    for (int r = 0; r < EPL; ++r) q[r] = buf[lane * EPL + r];
    for (int k2 = 2; k2 <= ELEMS; k2 <<= 1) {
        for (int j = k2 >> 1; j > 0; j >>= 1) {
            if (j >= EPL) {
                int lx = j / EPL;
#pragma unroll
                for (int r = 0; r < EPL; ++r) {
                    int idx = lane * EPL + r;
                    uint64_t o = __shfl_xor(q[r], lx, 64);
                    bool takeMin = (((idx & k2) == 0) == ((idx & j) == 0));
                    bool lt = q[r] < o;
                    uint64_t mn = lt ? q[r] : o, mx = lt ? o : q[r];
                    q[r] = takeMin ? mn : mx;
                }
            } else {
#pragma unroll
                for (int r = 0; r < EPL; ++r) {
                    if ((r & j) == 0) {
                        int rh = r | j;
                        int idx = lane * EPL + r;
                        bool up = ((idx & k2) == 0);
                        uint64_t a = q[r], c2 = q[rh];
                        bool lt = a < c2;
                        uint64_t mn = lt ? a : c2, mx = lt ? c2 : a;
                        q[r] = up ? mn : mx; q[rh] = up ? mx : mn;
                    }
                }
            }
        }
    }
#pragma unroll
    for (int r = 0; r < EPL; ++r) buf[lane * EPL + r] = q[r];
}

// Phase C batched: 2 windows of 64 per barrier pair (validated R12 body) — used for
// M in (256,512] and the full-sort fallback.
__device__ __forceinline__ int phaseC2(
    const uint64_t* keys, int nv, const float4* sboxp, float off,
    uint64_t* s_cp1, uint64_t* s_cpX, uint64_t* s_cp2,
    uint64_t* s_in1, uint64_t* s_in2,
    float4* s_kbox, float* s_karea, int* s_keep, int* s_kept, int lane, int wv)
{
    int c = 0;
    while (true) {
        __syncthreads();
        int kept = *s_kept;
        if (c >= nv || kept >= KDET) break;
        int W  = nv - c;
        int W1 = W < 64 ? W : 64;
        int W2 = (W > 64) ? ((W - 64) < 64 ? (W - 64) : 64) : 0;
        bool have1 = lane < W1, have2 = lane < W2;

        float ax1=0.f, ay1=0.f, ax2=0.f, ay2=0.f, aa=0.f;
        float bx1=0.f, by1=0.f, bx2=0.f, by2=0.f, ba=0.f;
        if (have1) {
            float4 bx = sboxp[(uint32_t)keys[c + lane]];
            ax1 = __fadd_rn(bx.x, off); ay1 = __fadd_rn(bx.y, off);
            ax2 = __fadd_rn(bx.z, off); ay2 = __fadd_rn(bx.w, off);
            aa  = __fmul_rn(__fsub_rn(ax2, ax1), __fsub_rn(ay2, ay1));
        }
        if (have2) {
            float4 bx = sboxp[(uint32_t)keys[c + 64 + lane]];
            bx1 = __fadd_rn(bx.x, off); by1 = __fadd_rn(bx.y, off);
            bx2 = __fadd_rn(bx.z, off); by2 = __fadd_rn(bx.w, off);
            ba  = __fmul_rn(__fsub_rn(bx2, bx1), __fsub_rn(by2, by1));
        }

        uint64_t cp1 = 0, cpX = 0, cp2 = 0;
#pragma unroll
        for (int t = 0; t < 8; ++t) {
            int i = wv + (t << 3);
            {
                bool rowok = (i < W1);
                int isrc = rowok ? i : 0;
                float rx1 = bcastf(ax1, isrc), ry1 = bcastf(ay1, isrc);
                float rx2 = bcastf(ax2, isrc), ry2 = bcastf(ay2, isrc);
                float ra  = bcastf(aa , isrc);
                bool p1 = rowok && have1 && (lane > i) &&
                          (iou5(rx1,ry1,rx2,ry2,ra, ax1,ay1,ax2,ay2,aa) > NMS_TH);
                uint64_t bm1 = (uint64_t)__ballot(p1);
                cp1 |= ((bm1 >> lane) & 1ull) << isrc;
                bool px = rowok && have2 &&
                          (iou5(rx1,ry1,rx2,ry2,ra, bx1,by1,bx2,by2,ba) > NMS_TH);
                uint64_t bmx = (uint64_t)__ballot(px);
                cpX |= ((bmx >> lane) & 1ull) << isrc;
            }
            {
                bool rowok = (i < W2);
                int isrc = rowok ? i : 0;
                float rx1 = bcastf(bx1, isrc), ry1 = bcastf(by1, isrc);
                float rx2 = bcastf(bx2, isrc), ry2 = bcastf(by2, isrc);
                float ra  = bcastf(ba , isrc);
                bool p2 = rowok && have2 && (lane > i) &&
                          (iou5(rx1,ry1,rx2,ry2,ra, bx1,by1,bx2,by2,ba) > NMS_TH);
                uint64_t bm2 = (uint64_t)__ballot(p2);
                cp2 |= ((bm2 >> lane) & 1ull) << isrc;
            }
        }
        s_cp1[(wv << 6) | lane] = cp1;
        s_cpX[(wv << 6) | lane] = cpX;
        s_cp2[(wv << 6) | lane] = cp2;

        bool si1 = false, si2 = false;
        if (kept) {
            for (int ki = wv; ki < kept; ki += 8) {
                float4 ko = s_kbox[ki];
                float  ka = s_karea[ki];
                si1 = si1 || (have1 && iou5(ko.x,ko.y,ko.z,ko.w,ka, ax1,ay1,ax2,ay2,aa) > NMS_TH);
                si2 = si2 || (have2 && iou5(ko.x,ko.y,ko.z,ko.w,ka, bx1,by1,bx2,by2,ba) > NMS_TH);
            }
        }
        uint64_t i1b = (uint64_t)__ballot(si1);
        uint64_t i2b = (uint64_t)__ballot(si2);
        if (lane == 0) { s_in1[wv] = i1b; s_in2[wv] = i2b; }
        __syncthreads();

        if (wv == 0) {
            uint64_t col1 = 0, colX = 0, col2 = 0, in1 = 0, in2 = 0;
#pragma unroll
            for (int w2i = 0; w2i < 8; ++w2i) {
                col1 |= s_cp1[(w2i << 6) | lane];
                colX |= s_cpX[(w2i << 6) | lane];
                col2 |= s_cp2[(w2i << 6) | lane];
                in1  |= s_in1[w2i];
                in2  |= s_in2[w2i];
            }
            uint64_t below = ~(~0ull << lane);

            bool alive1 = have1 && !((in1 >> lane) & 1ull);
            uint64_t keepM1 = (uint64_t)__ballot(alive1);
            for (int it = 0; it < 64; ++it) {
                uint64_t nk = (uint64_t)__ballot(alive1 && ((col1 & keepM1) == 0ull));
                if (nk == keepM1) break;
                keepM1 = nk;
            }
            int quota = KDET - kept;
            int n1 = __popcll(keepM1);
            int take1 = n1 < quota ? n1 : quota;
            int rank1 = __popcll(keepM1 & below);
            if ((((keepM1 >> lane) & 1ull) != 0ull) && rank1 < quota) {
                s_keep[kept + rank1]  = c + lane;
                s_kbox[kept + rank1]  = make_float4(ax1, ay1, ax2, ay2);
                s_karea[kept + rank1] = aa;
            }
            int kept1 = kept + take1;
            int take2 = 0;
            if (kept1 < KDET && W2 > 0) {
                bool alive2 = have2 && !((in2 >> lane) & 1ull) && ((colX & keepM1) == 0ull);
                uint64_t keepM2 = (uint64_t)__ballot(alive2);
                for (int it = 0; it < 64; ++it) {
                    uint64_t nk = (uint64_t)__ballot(alive2 && ((col2 & keepM2) == 0ull));
                    if (nk == keepM2) break;
                    keepM2 = nk;
                }
                int quota2 = KDET - kept1;
                int n2 = __popcll(keepM2);
                take2 = n2 < quota2 ? n2 : quota2;
                int rank2 = __popcll(keepM2 & below);
                if ((((keepM2 >> lane) & 1ull) != 0ull) && rank2 < quota2) {
                    s_keep[kept1 + rank2]  = c + 64 + lane;
                    s_kbox[kept1 + rank2]  = make_float4(bx1, by1, bx2, by2);
                    s_karea[kept1 + rank2] = ba;
                }
            }
            if (lane == 0) *s_kept = kept1 + take2;
        }
        c += 128;
    }
    __syncthreads();
    return *s_kept;
}

// ===================== main kernel (single dispatch) =====================
__global__ __launch_bounds__(BT) void PRISM_71511205479155_kernel(
    const float* __restrict__ clss, const float* __restrict__ regs,
    const float* __restrict__ qlts, const float* __restrict__ props,
    float* __restrict__ out, int B)
{
    __shared__ float4   sbox[NPROP];                 // 32K decoded boxes
    __shared__ __align__(16) char s_reg1[16384];     // union: {hist+cand} fast | {skey} fallback
    __shared__ __align__(16) char s_reg2[12288];     // union: {cp1,cpX,cp2} | {s_col 8K}
    __shared__ uint64_t s_in1[8], s_in2[8];
    __shared__ float4   s_kbox[KDET];
    __shared__ float    s_karea[KDET];
    __shared__ int      s_keep[KDET];
    __shared__ int      s_wsum[8];
    __shared__ int      s_maxc, s_kept, s_beta, s_M, s_totV, s_fb;

    uint32_t* hist = (uint32_t*)s_reg1;              // 512 words = 1024 buckets (u16 x2)
    uint64_t* cand = (uint64_t*)(s_reg1 + 2048);     // 512 keys
    uint64_t* skey = (uint64_t*)s_reg1;              // 2048 keys (fallback)
    uint64_t* s_cp1 = (uint64_t*)s_reg2;             // 512 u64
    uint64_t* s_cpX = (uint64_t*)(s_reg2 + 4096);
    uint64_t* s_cp2 = (uint64_t*)(s_reg2 + 8192);
    uint64_t* s_col = (uint64_t*)s_reg2;             // 1024 u64 (one-shot col masks)

    const int b = blockIdx.x, tid = threadIdx.x, lane = tid & 63, wv = tid >> 6;
    const int idxBase = (wv << 8) | (lane << 2);

    hist[tid & 511] = 0;
    if (tid == 0) { s_maxc = 0; s_kept = 0; s_beta = -1; s_M = 0; s_totV = 0; s_fb = 0; }
    __syncthreads();

    // ---- Phase A: decode + histogram (bucket = top 11 key bits; valid => <1024) ----
    uint64_t key[4];
    float thmax = 0.0f;
#pragma unroll
    for (int r = 0; r < 4; ++r) {
        int i = idxBase + r;
        float4 bx; uint64_t k; float mx;
        decode_one(clss, regs, qlts, props, b, i, bx, k, mx);
        sbox[i] = bx; key[r] = k;
        thmax = fmaxf(thmax, mx);
        uint32_t bkt = (uint32_t)(k >> 53);
        if (bkt < 1024)
            atomicAdd(&hist[bkt >> 1], (bkt & 1) ? 0x10000u : 1u);
    }
#pragma unroll
    for (int d = 1; d < 64; d <<= 1) thmax = fmaxf(thmax, __shfl_xor(thmax, d, 64));
    if (lane == 0) atomicMax(&s_maxc, __float_as_int(thmax)); // coords>=0: int cmp == float cmp
    __syncthreads();

    // ---- select boundary bucket for rank min(192, totalValid) ----
    {
        uint32_t wword = hist[tid & 511];
        uint32_t c0 = wword & 0xFFFFu, c1 = wword >> 16;
        uint32_t local = c0 + c1;
        uint32_t incl = local;
#pragma unroll
        for (int d = 1; d < 64; d <<= 1) {
            uint32_t v = __shfl_up(incl, d, 64);
            if (lane >= d) incl += v;
        }
        if (lane == 63) s_wsum[wv] = (int)incl;
        __syncthreads();
        int base = 0, tot = 0;
#pragma unroll
        for (int w = 0; w < 8; ++w) {
            int sv = s_wsum[w];
            tot += sv;
            if (w < wv) base += sv;
        }
        int target = tot < 192 ? tot : 192;
        uint32_t run = (uint32_t)base + incl - local;  // exclusive prefix at bucket 2*tid
        uint32_t cc2[2] = {c0, c1};
#pragma unroll
        for (int r = 0; r < 2; ++r) {
            uint32_t ci = run + cc2[r];
            if (target > 0 && (int)run < target && (int)ci >= target) {  // unique crossing
                s_beta = 2 * tid + r;
                s_M = (int)ci;
                if (ci > 512) s_fb = 1;
            }
            run = ci;
        }
        if (tid == 0) s_totV = tot;
        __syncthreads();
    }

    const float off = __fadd_rn(__int_as_float(s_maxc), 1.0f); // class-1 batched-NMS offset
    const int beta = s_beta, M = s_M, totV = s_totV;
    int fb = s_fb;
    bool oneshot = (!fb && M > 0 && M <= 256);

    if (!fb && M > 0) {
        // ---- ballot compaction of keys with bucket <= beta (order-free; sort follows) ----
        bool pr[4]; uint64_t bal[4]; int wcnt[4];
#pragma unroll
        for (int r = 0; r < 4; ++r) {
            pr[r]  = ((int)(key[r] >> 53) <= beta);
            bal[r] = (uint64_t)__ballot(pr[r]);
            wcnt[r] = __popcll(bal[r]);
        }
        int wtot = wcnt[0] + wcnt[1] + wcnt[2] + wcnt[3];
        if (lane == 0) s_wsum[wv] = wtot;
        __syncthreads();
        int base2 = 0;
#pragma unroll
        for (int w = 0; w < 8; ++w) if (w < wv) base2 += s_wsum[w];
        uint64_t below = ~(~0ull << lane);
        int roff = 0;
#pragma unroll
        for (int r = 0; r < 4; ++r) {
            if (pr[r]) {
                int pos = base2 + roff + __popcll(bal[r] & below);
                cand[pos] = key[r];
            }
            roff += wcnt[r];
        }
        int sortN = (M <= 256) ? 256 : 512;
        for (int t = M + tid; t < sortN; t += BT) cand[t] = ~0ull;   // pad sorts last
        if (oneshot) { s_col[tid] = 0; s_col[tid + 512] = 0; }       // zero col masks
        __syncthreads();

        // ---- wave 0: in-wave bitonic sort (zero barriers) ----
        if (wv == 0) {
            if (sortN == 256) wavesortN<256, 4>(cand, lane);
            else              wavesortN<512, 8>(cand, lane);
        }
        __syncthreads();
    }

    int kept = 0;
    if (oneshot) {
        // ---- one-shot NMS over <=256 candidates: single barrier pair ----
        // lane owns candidates j = 64w + lane, w = 0..3
        float qx1[4], qy1[4], qx2[4], qy2[4], qa[4];
        bool  qv[4];
#pragma unroll
        for (int w = 0; w < 4; ++w) {
            int j = (w << 6) | lane;
            qv[w] = (j < M);
            qx1[w] = qy1[w] = qx2[w] = qy2[w] = qa[w] = 0.f;
            if (qv[w]) {
                float4 bx = sbox[(uint32_t)cand[j]];
                qx1[w] = __fadd_rn(bx.x, off); qy1[w] = __fadd_rn(bx.y, off);
                qx2[w] = __fadd_rn(bx.z, off); qy2[w] = __fadd_rn(bx.w, off);
                qa[w]  = __fmul_rn(__fsub_rn(qx2[w], qx1[w]), __fsub_rn(qy2[w], qy1[w]));
            }
        }

        // upper-triangular suppression matrix; lane accumulates its own column bits
        uint64_t colM[4][4] = {{0,0,0,0},{0,0,0,0},{0,0,0,0},{0,0,0,0}};
        const int nW = (M + 63) >> 6;
#pragma unroll
        for (int wr = 0; wr < 4; ++wr) {
            if (wr < nW) {
#pragma unroll
                for (int t = 0; t < 8; ++t) {
                    int il = wv + (t << 3);
                    int gi = (wr << 6) | il;
                    bool rowok = (gi < M);
                    float rx1 = bcastf(qx1[wr], il), ry1 = bcastf(qy1[wr], il);
                    float rx2 = bcastf(qx2[wr], il), ry2 = bcastf(qy2[wr], il);
                    float ra  = bcastf(qa[wr],  il);
#pragma unroll
                    for (int w = 0; w < 4; ++w) {
                        if (w >= wr) {   // w<wr blocks have gj<gi always
                            int gj = (w << 6) | lane;
                            bool pred = rowok && qv[w] && (gj > gi) &&
                                (iou5(rx1,ry1,rx2,ry2,ra,
                                      qx1[w],qy1[w],qx2[w],qy2[w],qa[w]) > NMS_TH);
                            uint64_t bm = (uint64_t)__ballot(pred);
                            colM[w][wr] |= ((bm >> lane) & 1ull) << il;
                        }
                    }
                }
            }
        }
        // sparse OR-reduce partials into s_col[(j<<2)|wr]
#pragma unroll
        for (int w = 0; w < 4; ++w) {
#pragma unroll
            for (int wr = 0; wr < 4; ++wr) {
                if (colM[w][wr])
                    atomicOr((unsigned long long*)&s_col[((((w << 6) | lane)) << 2) | wr],
                             (unsigned long long)colM[w][wr]);
            }
        }
        __syncthreads();

        // wave 0: 256-bit Jacobi fixpoint (forward DAG => unique fixpoint == greedy)
        if (wv == 0) {
            uint64_t cR[4][4];
#pragma unroll
            for (int w = 0; w < 4; ++w)
#pragma unroll
                for (int wr = 0; wr < 4; ++wr)
                    cR[w][wr] = s_col[((((w << 6) | lane)) << 2) | wr];

            bool alive[4]; uint64_t K[4];
#pragma unroll
            for (int w = 0; w < 4; ++w) {
                alive[w] = (((w << 6) | lane) < M);
                K[w] = (uint64_t)__ballot(alive[w]);
            }
            for (int it = 0; it < 256; ++it) {
                bool p0 = alive[0] && (((cR[0][0]&K[0])|(cR[0][1]&K[1])|(cR[0][2]&K[2])|(cR[0][3]&K[3])) == 0ull);
                bool p1 = alive[1] && (((cR[1][0]&K[0])|(cR[1][1]&K[1])|(cR[1][2]&K[2])|(cR[1][3]&K[3])) == 0ull);
                bool p2 = alive[2] && (((cR[2][0]&K[0])|(cR[2][1]&K[1])|(cR[2][2]&K[2])|(cR[2][3]&K[3])) == 0ull);
                bool p3 = alive[3] && (((cR[3][0]&K[0])|(cR[3][1]&K[1])|(cR[3][2]&K[2])|(cR[3][3]&K[3])) == 0ull);
                uint64_t n0 = (uint64_t)__ballot(p0);
                uint64_t n1 = (uint64_t)__ballot(p1);
                uint64_t n2 = (uint64_t)__ballot(p2);
                uint64_t n3 = (uint64_t)__ballot(p3);
                bool same = (n0 == K[0]) && (n1 == K[1]) && (n2 == K[2]) && (n3 == K[3]);
                K[0] = n0; K[1] = n1; K[2] = n2; K[3] = n3;
                if (same) break;
            }
            // quota-truncated rank write (exact: greedy ignores quota for suppression)
            int t0 = __popcll(K[0]), t1 = __popcll(K[1]), t2 = __popcll(K[2]), t3 = __popcll(K[3]);
            int total = t0 + t1 + t2 + t3;
            uint64_t below = ~(~0ull << lane);
            int bases[4] = {0, t0, t0 + t1, t0 + t1 + t2};
#pragma unroll
            for (int w = 0; w < 4; ++w) {
                if ((K[w] >> lane) & 1ull) {
                    int rank = bases[w] + __popcll(K[w] & below);
                    if (rank < KDET) s_keep[rank] = (w << 6) | lane;
                }
            }
            if (lane == 0) s_kept = total < KDET ? total : KDET;
        }
        __syncthreads();
        kept = s_kept;
    } else if (!fb && M > 0) {
        // M in (256,512]: validated 2-window path
        kept = phaseC2(cand, M, sbox, off, s_cp1, s_cpX, s_cp2, s_in1, s_in2,
                       s_kbox, s_karea, s_keep, &s_kept, lane, wv);
    }

    // ---- fallback: selection overflow, or quota unmet with more candidates ----
    bool needFull = fb || (kept < KDET && M < totV);
    if (needFull) {
        __syncthreads();
        if (tid == 0) s_kept = 0;
        bitonic2048(key, skey, idxBase, lane);   // key[4] regs intact since Phase A
        __syncthreads();
#pragma unroll
        for (int r = 0; r < 4; ++r) skey[idxBase + r] = key[r];
        kept = phaseC2(skey, totV, sbox, off, s_cp1, s_cpX, s_cp2, s_in1, s_in2,
                       s_kbox, s_karea, s_keep, &s_kept, lane, wv);
    }
    const uint64_t* fkeys = needFull ? skey : cand;

    // ---- Phase D: parallel output write + zero-fill ----
    float* out_boxes  = out;
    float* out_scores = out + (size_t)B * KDET * 4;
    float* out_cls    = out + (size_t)B * KDET * 5;
    for (int s = tid; s < KDET; s += BT) {
        float* ob = out_boxes + ((size_t)b * KDET + s) * 4;
        if (s < kept) {
            uint64_t kk = fkeys[s_keep[s]];
            float4 bx = sbox[(uint32_t)kk];
            ob[0] = bx.x; ob[1] = bx.y; ob[2] = bx.z; ob[3] = bx.w;
            out_scores[(size_t)b * KDET + s] = dec_score(kk);
            out_cls[(size_t)b * KDET + s]    = 1.0f;
        } else {
            ob[0] = 0.0f; ob[1] = 0.0f; ob[2] = 0.0f; ob[3] = 0.0f;
            out_scores[(size_t)b * KDET + s] = 0.0f;
            out_cls[(size_t)b * KDET + s]    = 0.0f;
        }
    }
}

extern "C" void kernel_launch(void* const* d_in, const int* in_sizes, int n_in,
                              void* d_out, int out_size, void* d_ws, size_t ws_size,
                              hipStream_t stream) {
    const float* clss  = (const float*)d_in[0];  // [B,N,2]
    const float* regs  = (const float*)d_in[1];  // [B,N,4]
    const float* qlts  = (const float*)d_in[2];  // [B,N,1]
    const float* props = (const float*)d_in[3];  // [B,N,4]
    float* out = (float*)d_out;

    int B = in_sizes[0] / (NPROP * NCLS);

    PRISM_71511205479155_kernel<<<B, BT, 0, stream>>>(clss, regs, qlts, props, out, B);
}

// Round 14
// 33.648 us; speedup vs baseline: 1.0379x; 1.0379x over previous
//
#include <hip/hip_runtime.h>
#include <stdint.h>

#define NPROP 2048
#define NCLS  2
#define KDET  100
#define BT    512
#define NMS_TH 0.4f

// decode the monotone-encoded score from the high word of a sort key
__device__ __forceinline__ float dec_score(uint64_t k) {
    uint32_t u = ~(uint32_t)(k >> 32);
    uint32_t bits = (u & 0x80000000u) ? (u & 0x7FFFFFFFu) : ~u;
    return __uint_as_float(bits);
}

// wave-uniform lane broadcast via v_readlane (no DS op; bit-exact)
__device__ __forceinline__ float bcastf(float v, int srclane) {
    return __uint_as_float((uint32_t)__builtin_amdgcn_readlane(__float_as_int(v), srclane));
}

// reference-rounding IoU on offset coords (a vs b), both precomputed with areas
__device__ __forceinline__ float iou5(float ax1, float ay1, float ax2, float ay2, float aa,
                                      float bx1, float by1, float bx2, float by2, float ba) {
    float ltx = fmaxf(ax1, bx1), lty = fmaxf(ay1, by1);
    float rbx = fminf(ax2, bx2), rby = fminf(ay2, by2);
    float iw = fmaxf(__fsub_rn(rbx, ltx), 0.0f);
    float ih = fmaxf(__fsub_rn(rby, lty), 0.0f);
    float inter = __fmul_rn(iw, ih);
    float denom = __fadd_rn(__fsub_rn(__fadd_rn(aa, ba), inter), 1e-9f);
    return __fdiv_rn(inter, denom);
}

// decode+clip+score one proposal from pre-loaded values: arithmetic bit-identical
// to the validated R5/R12 path (only the load shape changed — G13 vectorization).
__device__ __forceinline__ void decode_core(
    float4 p, float4 rg, float2 cc, float qv, int i,
    float4& boxOut, uint64_t& keyOut, float& mxOut)
{
    const float CLIPV = 4.135166556742356f;   // log(1000/16)
    float w  = __fsub_rn(p.z, p.x);
    float h  = __fsub_rn(p.w, p.y);
    float cx = __fadd_rn(p.x, __fmul_rn(0.5f, w));
    float cy = __fadd_rn(p.y, __fmul_rn(0.5f, h));
    float dx = __fdiv_rn(rg.x, 10.0f);
    float dy = __fdiv_rn(rg.y, 10.0f);
    float dw = fminf(__fdiv_rn(rg.z, 5.0f), CLIPV);
    float dh = fminf(__fdiv_rn(rg.w, 5.0f), CLIPV);
    float pcx = __fadd_rn(__fmul_rn(dx, w), cx);
    float pcy = __fadd_rn(__fmul_rn(dy, h), cy);
    float pw  = __fmul_rn(expf(dw), w);
    float ph  = __fmul_rn(expf(dh), h);
    float x1 = __fsub_rn(pcx, __fmul_rn(0.5f, pw));
    float y1 = __fsub_rn(pcy, __fmul_rn(0.5f, ph));
    float x2 = __fadd_rn(pcx, __fmul_rn(0.5f, pw));
    float y2 = __fadd_rn(pcy, __fmul_rn(0.5f, ph));
    x1 = fminf(fmaxf(x1, 0.0f), 512.0f);
    y1 = fminf(fmaxf(y1, 0.0f), 512.0f);
    x2 = fminf(fmaxf(x2, 0.0f), 512.0f);
    y2 = fminf(fmaxf(y2, 0.0f), 512.0f);
    bool small_ok = (__fsub_rn(x2, x1) >= 0.01f) && (__fsub_rn(y2, y1) >= 0.01f);

    float m  = fmaxf(cc.x, cc.y);
    float e0 = expf(__fsub_rn(cc.x, m));
    float e1 = expf(__fsub_rn(cc.y, m));
    float raw = __fdiv_rn(e1, __fadd_rn(e0, e1));
    float sq  = __fdiv_rn(1.0f, __fadd_rn(1.0f, expf(-qv)));
    float score = __fmul_rn(sq, raw);
    bool valid = (raw > 0.05f) && small_ok;
    float masked = valid ? score : -1.0f;

    boxOut = make_float4(x1, y1, x2, y2);
    uint32_t fb = __float_as_uint(masked);
    uint32_t u  = (fb & 0x80000000u) ? ~fb : (fb | 0x80000000u); // monotone encode
    keyOut = ((uint64_t)(~u) << 32) | (uint32_t)i;               // asc = score desc, idx asc
    mxOut = fmaxf(fmaxf(x1, y1), fmaxf(x2, y2));
}

// register-resident bitonic sort of 2048 u64 keys (4 consecutive/thread) — fallback path
__device__ __forceinline__ void bitonic2048(uint64_t key[4], uint64_t* skey,
                                            int idxBase, int lane)
{
    for (int k = 2; k <= NPROP; k <<= 1) {
        for (int j = k >> 1; j > 0; j >>= 1) {
            if (j >= 256) {
                __syncthreads();
#pragma unroll
                for (int r = 0; r < 4; ++r) {
                    int idx = idxBase + r;
                    skey[(idx >> 2) | ((idx & 3) << 9)] = key[r];
                }
                __syncthreads();
#pragma unroll
                for (int r = 0; r < 4; ++r) {
                    int idx  = idxBase + r;
                    int pidx = idx ^ j;
                    uint64_t o = skey[(pidx >> 2) | ((pidx & 3) << 9)];
                    bool takeMin = (((idx & k) == 0) == ((idx & j) == 0));
                    bool lt = key[r] < o;
                    uint64_t mn = lt ? key[r] : o, mx = lt ? o : key[r];
                    key[r] = takeMin ? mn : mx;
                }
            } else if (j >= 4) {
                int lx = j >> 2;
#pragma unroll
                for (int r = 0; r < 4; ++r) {
                    int idx = idxBase + r;
                    uint64_t o = __shfl_xor(key[r], lx, 64);
                    bool takeMin = (((idx & k) == 0) == ((lane & lx) == 0));
                    bool lt = key[r] < o;
                    uint64_t mn = lt ? key[r] : o, mx = lt ? o : key[r];
                    key[r] = takeMin ? mn : mx;
                }
            } else {
#pragma unroll
                for (int r = 0; r < 4; ++r) {
                    if ((r & j) == 0) {
                        int rh = r | j;
                        int idx = idxBase + r;
                        bool up = ((idx & k) == 0);
                        uint64_t a = key[r], c2 = key[rh];
                        bool lt = a < c2;
                        uint64_t mn = lt ? a : c2, mx = lt ? c2 : a;
                        key[r] = up ? mn : mx; key[rh] = up ? mx : mn;
                    }
                }
            }
        }
    }
}

// in-wave bitonic sort of ELEMS u64 keys, EPL keys/lane (wave 0 only; zero barriers)
template<int ELEMS, int EPL>
__device__ __forceinline__ void wavesortN(uint64_t* buf, int lane)
{
    uint64_t q[EPL];
#pragma unroll
    for (int r = 0; r < EPL; ++r) q[r] = buf[lane * EPL + r];
    for (int k2 = 2; k2 <= ELEMS; k2 <<= 1) {
        for (int j = k2 >> 1; j > 0; j >>= 1) {
            if (j >= EPL) {
                int lx = j / EPL;
#pragma unroll
                for (int r = 0; r < EPL; ++r) {
                    int idx = lane * EPL + r;
                    uint64_t o = __shfl_xor(q[r], lx, 64);
                    bool takeMin = (((idx & k2) == 0) == ((idx & j) == 0));
                    bool lt = q[r] < o;
                    uint64_t mn = lt ? q[r] : o, mx = lt ? o : q[r];
                    q[r] = takeMin ? mn : mx;
                }
            } else {
#pragma unroll
                for (int r = 0; r < EPL; ++r) {
                    if ((r & j) == 0) {
                        int rh = r | j;
                        int idx = lane * EPL + r;
                        bool up = ((idx & k2) == 0);
                        uint64_t a = q[r], c2 = q[rh];
                        bool lt = a < c2;
                        uint64_t mn = lt ? a : c2, mx = lt ? c2 : a;
                        q[r] = up ? mn : mx; q[rh] = up ? mx : mn;
                    }
                }
            }
        }
    }
#pragma unroll
    for (int r = 0; r < EPL; ++r) buf[lane * EPL + r] = q[r];
}

// Phase C batched: 2 windows of 64 per barrier pair; exact greedy semantics (validated R12)
__device__ __forceinline__ int phaseC2(
    const uint64_t* keys, int nv, const float4* sboxp, float off,
    uint64_t* s_cp1, uint64_t* s_cpX, uint64_t* s_cp2,
    uint64_t* s_in1, uint64_t* s_in2,
    float4* s_kbox, float* s_karea, int* s_keep, int* s_kept, int lane, int wv)
{
    int c = 0;
    while (true) {
        __syncthreads();
        int kept = *s_kept;
        if (c >= nv || kept >= KDET) break;
        int W  = nv - c;
        int W1 = W < 64 ? W : 64;
        int W2 = (W > 64) ? ((W - 64) < 64 ? (W - 64) : 64) : 0;
        bool have1 = lane < W1, have2 = lane < W2;

        float ax1=0.f, ay1=0.f, ax2=0.f, ay2=0.f, aa=0.f;
        float bx1=0.f, by1=0.f, bx2=0.f, by2=0.f, ba=0.f;
        if (have1) {
            float4 bx = sboxp[(uint32_t)keys[c + lane]];
            ax1 = __fadd_rn(bx.x, off); ay1 = __fadd_rn(bx.y, off);
            ax2 = __fadd_rn(bx.z, off); ay2 = __fadd_rn(bx.w, off);
            aa  = __fmul_rn(__fsub_rn(ax2, ax1), __fsub_rn(ay2, ay1));
        }
        if (have2) {
            float4 bx = sboxp[(uint32_t)keys[c + 64 + lane]];
            bx1 = __fadd_rn(bx.x, off); by1 = __fadd_rn(bx.y, off);
            bx2 = __fadd_rn(bx.z, off); by2 = __fadd_rn(bx.w, off);
            ba  = __fmul_rn(__fsub_rn(bx2, bx1), __fsub_rn(by2, by1));
        }

        uint64_t cp1 = 0, cpX = 0, cp2 = 0;
#pragma unroll
        for (int t = 0; t < 8; ++t) {
            int i = wv + (t << 3);
            {
                bool rowok = (i < W1);
                int isrc = rowok ? i : 0;
                float rx1 = bcastf(ax1, isrc), ry1 = bcastf(ay1, isrc);
                float rx2 = bcastf(ax2, isrc), ry2 = bcastf(ay2, isrc);
                float ra  = bcastf(aa , isrc);
                bool p1 = rowok && have1 && (lane > i) &&
                          (iou5(rx1,ry1,rx2,ry2,ra, ax1,ay1,ax2,ay2,aa) > NMS_TH);
                uint64_t bm1 = (uint64_t)__ballot(p1);
                cp1 |= ((bm1 >> lane) & 1ull) << isrc;
                bool px = rowok && have2 &&
                          (iou5(rx1,ry1,rx2,ry2,ra, bx1,by1,bx2,by2,ba) > NMS_TH);
                uint64_t bmx = (uint64_t)__ballot(px);
                cpX |= ((bmx >> lane) & 1ull) << isrc;
            }
            {
                bool rowok = (i < W2);
                int isrc = rowok ? i : 0;
                float rx1 = bcastf(bx1, isrc), ry1 = bcastf(by1, isrc);
                float rx2 = bcastf(bx2, isrc), ry2 = bcastf(by2, isrc);
                float ra  = bcastf(ba , isrc);
                bool p2 = rowok && have2 && (lane > i) &&
                          (iou5(rx1,ry1,rx2,ry2,ra, bx1,by1,bx2,by2,ba) > NMS_TH);
                uint64_t bm2 = (uint64_t)__ballot(p2);
                cp2 |= ((bm2 >> lane) & 1ull) << isrc;
            }
        }
        s_cp1[(wv << 6) | lane] = cp1;
        s_cpX[(wv << 6) | lane] = cpX;
        s_cp2[(wv << 6) | lane] = cp2;

        bool si1 = false, si2 = false;
        if (kept) {
            for (int ki = wv; ki < kept; ki += 8) {
                float4 ko = s_kbox[ki];
                float  ka = s_karea[ki];
                si1 = si1 || (have1 && iou5(ko.x,ko.y,ko.z,ko.w,ka, ax1,ay1,ax2,ay2,aa) > NMS_TH);
                si2 = si2 || (have2 && iou5(ko.x,ko.y,ko.z,ko.w,ka, bx1,by1,bx2,by2,ba) > NMS_TH);
            }
        }
        uint64_t i1b = (uint64_t)__ballot(si1);
        uint64_t i2b = (uint64_t)__ballot(si2);
        if (lane == 0) { s_in1[wv] = i1b; s_in2[wv] = i2b; }
        __syncthreads();

        if (wv == 0) {
            uint64_t col1 = 0, colX = 0, col2 = 0, in1 = 0, in2 = 0;
#pragma unroll
            for (int w2i = 0; w2i < 8; ++w2i) {
                col1 |= s_cp1[(w2i << 6) | lane];
                colX |= s_cpX[(w2i << 6) | lane];
                col2 |= s_cp2[(w2i << 6) | lane];
                in1  |= s_in1[w2i];
                in2  |= s_in2[w2i];
            }
            uint64_t below = ~(~0ull << lane);

            bool alive1 = have1 && !((in1 >> lane) & 1ull);
            uint64_t keepM1 = (uint64_t)__ballot(alive1);
            for (int it = 0; it < 64; ++it) {
                uint64_t nk = (uint64_t)__ballot(alive1 && ((col1 & keepM1) == 0ull));
                if (nk == keepM1) break;
                keepM1 = nk;
            }
            int quota = KDET - kept;
            int n1 = __popcll(keepM1);
            int take1 = n1 < quota ? n1 : quota;
            int rank1 = __popcll(keepM1 & below);
            if ((((keepM1 >> lane) & 1ull) != 0ull) && rank1 < quota) {
                s_keep[kept + rank1]  = c + lane;
                s_kbox[kept + rank1]  = make_float4(ax1, ay1, ax2, ay2);
                s_karea[kept + rank1] = aa;
            }
            int kept1 = kept + take1;
            int take2 = 0;
            if (kept1 < KDET && W2 > 0) {
                bool alive2 = have2 && !((in2 >> lane) & 1ull) && ((colX & keepM1) == 0ull);
                uint64_t keepM2 = (uint64_t)__ballot(alive2);
                for (int it = 0; it < 64; ++it) {
                    uint64_t nk = (uint64_t)__ballot(alive2 && ((col2 & keepM2) == 0ull));
                    if (nk == keepM2) break;
                    keepM2 = nk;
                }
                int quota2 = KDET - kept1;
                int n2 = __popcll(keepM2);
                take2 = n2 < quota2 ? n2 : quota2;
                int rank2 = __popcll(keepM2 & below);
                if ((((keepM2 >> lane) & 1ull) != 0ull) && rank2 < quota2) {
                    s_keep[kept1 + rank2]  = c + 64 + lane;
                    s_kbox[kept1 + rank2]  = make_float4(bx1, by1, bx2, by2);
                    s_karea[kept1 + rank2] = ba;
                }
            }
            if (lane == 0) *s_kept = kept1 + take2;
        }
        c += 128;
    }
    __syncthreads();
    return *s_kept;
}

// ===================== main kernel (single dispatch) =====================
__global__ __launch_bounds__(BT) void PRISM_71511205479155_kernel(
    const float* __restrict__ clss, const float* __restrict__ regs,
    const float* __restrict__ qlts, const float* __restrict__ props,
    float* __restrict__ out, int B)
{
    __shared__ float4   sbox[NPROP];                 // 32K decoded boxes
    __shared__ __align__(16) char s_reg1[16384];     // union: {hist+cand} fast | {skey} fallback
    __shared__ uint64_t s_cp1[512];                  // 4K
    __shared__ uint64_t s_cpX[512];                  // 4K
    __shared__ uint64_t s_cp2[512];                  // 4K
    __shared__ uint64_t s_in1[8], s_in2[8];
    __shared__ float4   s_kbox[KDET];
    __shared__ float    s_karea[KDET];
    __shared__ int      s_keep[KDET];
    __shared__ int      s_wsum[8];
    __shared__ int      s_maxc, s_kept, s_beta, s_M, s_totV, s_fb;

    uint32_t* hist = (uint32_t*)s_reg1;              // 512 words = 1024 buckets (u16 x2)
    uint64_t* cand = (uint64_t*)(s_reg1 + 2048);     // 512 keys
    uint64_t* skey = (uint64_t*)s_reg1;              // 2048 keys (fallback)

    const int b = blockIdx.x, tid = threadIdx.x, lane = tid & 63, wv = tid >> 6;
    const int idxBase = (wv << 8) | (lane << 2);     // 4-aligned

    hist[tid & 511] = 0;
    if (tid == 0) { s_maxc = 0; s_kept = 0; s_beta = -1; s_M = 0; s_totV = 0; s_fb = 0; }
    __syncthreads();

    // ---- Phase A: decode + histogram (vectorized loads; arithmetic bit-identical) ----
    uint64_t key[4];
    float thmax = 0.0f;
    {
        size_t base = (size_t)b * NPROP + idxBase;
        float4 q4  = ((const float4*)qlts)[base >> 2];          // 4 consecutive qlts
        float4 cA  = ((const float4*)clss)[base >> 1];          // clss pairs for r=0,1
        float4 cB  = ((const float4*)clss)[(base >> 1) + 1];    // clss pairs for r=2,3
        float  qvA[4]  = {q4.x, q4.y, q4.z, q4.w};
        float2 ccA[4]  = {{cA.x, cA.y}, {cA.z, cA.w}, {cB.x, cB.y}, {cB.z, cB.w}};
#pragma unroll
        for (int r = 0; r < 4; ++r) {
            int i = idxBase + r;
            float4 p  = ((const float4*)props)[b * NPROP + i];
            float4 rg = ((const float4*)regs)[b * NPROP + i];
            float4 bx; uint64_t k; float mx;
            decode_core(p, rg, ccA[r], qvA[r], i, bx, k, mx);
            sbox[i] = bx; key[r] = k;
            thmax = fmaxf(thmax, mx);
            uint32_t bkt = (uint32_t)(k >> 53);
            if (bkt < 1024)
                atomicAdd(&hist[bkt >> 1], (bkt & 1) ? 0x10000u : 1u);
        }
    }
#pragma unroll
    for (int d = 1; d < 64; d <<= 1) thmax = fmaxf(thmax, __shfl_xor(thmax, d, 64));
    if (lane == 0) atomicMax(&s_maxc, __float_as_int(thmax)); // coords>=0: int cmp == float cmp
    __syncthreads();

    // ---- select boundary bucket for rank min(192, totalValid) ----
    {
        uint32_t wword = hist[tid & 511];
        uint32_t c0 = wword & 0xFFFFu, c1 = wword >> 16;
        uint32_t local = c0 + c1;
        uint32_t incl = local;
#pragma unroll
        for (int d = 1; d < 64; d <<= 1) {
            uint32_t v = __shfl_up(incl, d, 64);
            if (lane >= d) incl += v;
        }
        if (lane == 63) s_wsum[wv] = (int)incl;
        __syncthreads();
        int base = 0, tot = 0;
#pragma unroll
        for (int w = 0; w < 8; ++w) {
            int sv = s_wsum[w];
            tot += sv;
            if (w < wv) base += sv;
        }
        int target = tot < 192 ? tot : 192;
        uint32_t run = (uint32_t)base + incl - local;  // exclusive prefix at bucket 2*tid
        uint32_t cc2[2] = {c0, c1};
#pragma unroll
        for (int r = 0; r < 2; ++r) {
            uint32_t ci = run + cc2[r];
            if (target > 0 && (int)run < target && (int)ci >= target) {  // unique crossing
                s_beta = 2 * tid + r;
                s_M = (int)ci;
                if (ci > 512) s_fb = 1;
            }
            run = ci;
        }
        if (tid == 0) s_totV = tot;
        __syncthreads();
    }

    const float off = __fadd_rn(__int_as_float(s_maxc), 1.0f); // class-1 batched-NMS offset
    const int beta = s_beta, M = s_M, totV = s_totV;
    int fb = s_fb;

    if (!fb && M > 0) {
        // ---- ballot compaction of keys with bucket <= beta (order-free; sort follows) ----
        bool pr[4]; uint64_t bal[4]; int wcnt[4];
#pragma unroll
        for (int r = 0; r < 4; ++r) {
            pr[r]  = ((int)(key[r] >> 53) <= beta);
            bal[r] = (uint64_t)__ballot(pr[r]);
            wcnt[r] = __popcll(bal[r]);
        }
        int wtot = wcnt[0] + wcnt[1] + wcnt[2] + wcnt[3];
        if (lane == 0) s_wsum[wv] = wtot;
        __syncthreads();
        int base2 = 0;
#pragma unroll
        for (int w = 0; w < 8; ++w) if (w < wv) base2 += s_wsum[w];
        uint64_t below = ~(~0ull << lane);
        int roff = 0;
#pragma unroll
        for (int r = 0; r < 4; ++r) {
            if (pr[r]) {
                int pos = base2 + roff + __popcll(bal[r] & below);
                cand[pos] = key[r];
            }
            roff += wcnt[r];
        }
        int sortN = (M <= 256) ? 256 : 512;
        for (int t = M + tid; t < sortN; t += BT) cand[t] = ~0ull;   // pad sorts last
        __syncthreads();

        // ---- wave 0: in-wave bitonic sort (zero barriers) ----
        if (wv == 0) {
            if (sortN == 256) wavesortN<256, 4>(cand, lane);
            else              wavesortN<512, 8>(cand, lane);
        }
        __syncthreads();
    }

    // ---- Phase C on selected prefix ----
    int kept = 0;
    if (!fb && M > 0)
        kept = phaseC2(cand, M, sbox, off, s_cp1, s_cpX, s_cp2, s_in1, s_in2,
                       s_kbox, s_karea, s_keep, &s_kept, lane, wv);

    // ---- fallback: selection overflow, or quota unmet with more candidates ----
    bool needFull = fb || (kept < KDET && M < totV);
    if (needFull) {
        if (tid == 0) s_kept = 0;
        bitonic2048(key, skey, idxBase, lane);   // key[4] regs intact since Phase A
        __syncthreads();
#pragma unroll
        for (int r = 0; r < 4; ++r) skey[idxBase + r] = key[r];
        kept = phaseC2(skey, totV, sbox, off, s_cp1, s_cpX, s_cp2, s_in1, s_in2,
                       s_kbox, s_karea, s_keep, &s_kept, lane, wv);
    }
    const uint64_t* fkeys = needFull ? skey : cand;

    // ---- Phase D: parallel output write + zero-fill ----
    float* out_boxes  = out;
    float* out_scores = out + (size_t)B * KDET * 4;
    float* out_cls    = out + (size_t)B * KDET * 5;
    for (int s = tid; s < KDET; s += BT) {
        float* ob = out_boxes + ((size_t)b * KDET + s) * 4;
        if (s < kept) {
            uint64_t kk = fkeys[s_keep[s]];
            float4 bx = sbox[(uint32_t)kk];
            ob[0] = bx.x; ob[1] = bx.y; ob[2] = bx.z; ob[3] = bx.w;
            out_scores[(size_t)b * KDET + s] = dec_score(kk);
            out_cls[(size_t)b * KDET + s]    = 1.0f;
        } else {
            ob[0] = 0.0f; ob[1] = 0.0f; ob[2] = 0.0f; ob[3] = 0.0f;
            out_scores[(size_t)b * KDET + s] = 0.0f;
            out_cls[(size_t)b * KDET + s]    = 0.0f;
        }
    }
}

extern "C" void kernel_launch(void* const* d_in, const int* in_sizes, int n_in,
                              void* d_out, int out_size, void* d_ws, size_t ws_size,
                              hipStream_t stream) {
    const float* clss  = (const float*)d_in[0];  // [B,N,2]
    const float* regs  = (const float*)d_in[1];  // [B,N,4]
    const float* qlts  = (const float*)d_in[2];  // [B,N,1]
    const float* props = (const float*)d_in[3];  // [B,N,4]
    float* out = (float*)d_out;

    int B = in_sizes[0] / (NPROP * NCLS);

    PRISM_71511205479155_kernel<<<B, BT, 0, stream>>>(clss, regs, qlts, props, out, B);
}